// Round 11
// baseline (2108.283 us; speedup 1.0000x reference)
//
#include <hip/hip_runtime.h>

// LSTM B=512, T=512, H=256. Round 11: r10 H-split/4 + TWO staggered batch-sets.
// r10's 7400 cyc/step = LDS ~2000 + compute ~1000 + ~4400 EXPOSED LLC exchange
// chain (all waves in same phase -> chain serializes). Fix: 64 blocks (16 groups
// x 4 subs); group owns 32 batches = set A (16) + set B (16). Iteration:
//   [copyA|spin] b (1) [mfmaA] b (2) [nonlinA+publishA | spinB copyB] b (3,+flagA)
//   [mfmaB] b (4) [nonlinB+publishB] b (5,+flagB)
// A in-flight during phase B and vice versa -> LLC latency hidden behind the
// other set's compute. h_full rebuilt by copiers every phase (own tile also
// round-trips LLC: kills the nonlin h-scatter). Weights 128 KB LDS-resident.
// Safety per set = r10's argument (monotonic flags, parity tiles, co-resident).
// MFMA f32_16x16x32_f16: A=h[m=batch=l16][k], B=W[k][n=l16], D[m=quad*4+r][n].
// Weights prescaled by -log2e (i,f,o) / +2log2e (g).

typedef _Float16 half8 __attribute__((ext_vector_type(8)));
typedef float f32x4 __attribute__((ext_vector_type(4)));

constexpr int kT = 512;
constexpr int kHF = 264;   // h_full row stride (halves)
constexpr float kLog2e = 1.44269504088896340736f;

#define ATL(p)    __hip_atomic_load((p), __ATOMIC_RELAXED, __HIP_MEMORY_SCOPE_AGENT)
#define ATS(p, v) __hip_atomic_store((p), (v), __ATOMIC_RELAXED, __HIP_MEMORY_SCOPE_AGENT)

// ws layout (bytes):
//   [0, 524288)        weight fragments fp16 (as r10): frag (sub,c,g,kt) at half8
//                      idx (sub*128 + (c*4+g)*8 + kt)*64 + lane
//   [524288, 1048576)  gbuf: tile(set,bid,par) 2 KB at +((set*64+bid)*2+par)*2048
//                      layout [hl][m-groups-of-4] u64
//   [1048576, 1049088) flags int[2][64]
//   [1049088, 1057280) pbuf float[2][64][16]
__global__ void prep_weights(const float* __restrict__ W_hh, _Float16* __restrict__ ws)
{
    int gid = blockIdx.x * blockDim.x + threadIdx.x;  // 0..32767, one half8 each
    int lane = gid & 63;
    int f = (gid >> 6) & 127;
    int sub = gid >> 13;
    int kt = f & 7, g = (f >> 3) & 3, c = f >> 5;
    int R = g * 256 + sub * 64 + c * 16 + (lane & 15);
    int k = kt * 32 + (lane >> 4) * 8;
    float s = (g == 2) ? 2.0f * kLog2e : -kLog2e;
    const float* src = W_hh + R * 256 + k;
    half8 v;
    #pragma unroll
    for (int j = 0; j < 8; ++j) v[j] = (_Float16)(src[j] * s);
    reinterpret_cast<half8*>(ws)[gid] = v;
}

__device__ __forceinline__ f32x4 mfma16(half8 a, half8 b, f32x4 c) {
    return __builtin_amdgcn_mfma_f32_16x16x32_f16(a, b, c, 0, 0, 0);
}

__global__ __launch_bounds__(512, 2)
void lstm_main(const float* __restrict__ ts,
               const float* __restrict__ W_ih,
               const float* __restrict__ b_ih,
               const float* __restrict__ b_hh,
               const float* __restrict__ W_out,
               const _Float16* __restrict__ wfrag,
               unsigned short* __restrict__ gb,
               int* __restrict__ flags,
               float* __restrict__ pbuf)
{
    __shared__ __align__(16) _Float16 wlds[65536];        // 128 KB weights
    __shared__ __align__(16) _Float16 h_full[16][kHF];    // 8448 B, shared by phases
    __shared__ __align__(16) float pacc1[4][4][16][20];   // 20480 B
    __shared__ float red2[2][4][16];                      // 512 B

    const int tid  = threadIdx.x;
    const int w    = tid >> 6;
    const int lane = tid & 63;
    const int l16  = lane & 15;
    const int quad = lane >> 4;
    const int bid  = blockIdx.x;
    const int sub  = bid & 3;
    const int grp  = bid >> 2;
    const int b0A  = grp * 32;
    const int b0B  = grp * 32 + 16;
    const int c    = w & 3;
    const int kh   = w >> 2;

    const half8* wf8 = reinterpret_cast<const half8*>(wfrag) + sub * 8192;
    half8* wl8 = reinterpret_cast<half8*>(wlds);
    for (int i = tid; i < 8192; i += 512) wl8[i] = wf8[i];

    float wih[4], bias[4];
    if (w < 4) {
        #pragma unroll
        for (int g = 0; g < 4; ++g) {
            int R = g * 256 + sub * 64 + c * 16 + l16;
            float s = (g == 2) ? 2.0f * kLog2e : -kLog2e;
            wih[g]  = W_ih[R] * s;
            bias[g] = (b_ih[R] + b_hh[R]) * s;
        }
    }

    // copier mapping: every thread copies one (psub, half-tile) chunk per phase
    const int cs   = tid >> 7;
    const int psub = (sub + cs) & 3;
    const int pbid = (grp << 2) | psub;
    const int i0   = (tid & 127) * 2;      // u64 index within tile
    const int chl  = i0 >> 2;              // source hl 0..63
    const int cm0  = (i0 & 3) * 4;         // 0 or 8

    // tile base pointers (u64 units): tile(set,b,par) = gb64 + ((set*64+b)*2+par)*256
    unsigned long long* gb64 = reinterpret_cast<unsigned long long*>(gb);

    float cstA[4] = {0,0,0,0}, cstB[4] = {0,0,0,0};
    float oaccA[4] = {0,0,0,0}, oaccB[4] = {0,0,0,0};

    __syncthreads();

    for (int t = 0; t < kT; ++t) {
        const int wp = t & 1, rp = (t + 1) & 1;

        // ================= phase A =================
        {
            if (t > 0) {
                while (ATL(&flags[pbid]) < t) __builtin_amdgcn_s_sleep(1);
                asm volatile("" ::: "memory");
            }
            const unsigned long long* pt = gb64 + ((0 * 64 + pbid) * 2 + rp) * 256;
            unsigned long long d0 = ATL(pt + i0);
            unsigned long long d1 = ATL(pt + i0 + 1);
            union { unsigned long long u; unsigned short s[4]; } u0, u1;
            u0.u = d0; u1.u = d1;
            #pragma unroll
            for (int j = 0; j < 4; ++j) {
                reinterpret_cast<unsigned short*>(&h_full[cm0 + j][psub * 64 + chl])[0] = u0.s[j];
                reinterpret_cast<unsigned short*>(&h_full[cm0 + 4 + j][psub * 64 + chl])[0] = u1.s[j];
            }
        }
        __syncthreads();   // (1) h_full = set A h_{t-1}

        // prefetch VMEM for nonlin (both sets) early
        float tsvA[4], tsvB[4], wo = 0.f;
        if (w < 4) {
            #pragma unroll
            for (int r = 0; r < 4; ++r) {
                tsvA[r] = ts[(b0A + quad * 4 + r) * kT + t];
                tsvB[r] = ts[(b0B + quad * 4 + r) * kT + t];
            }
            wo = W_out[t * 256 + sub * 64 + c * 16 + l16];
        }

        // MFMA A
        {
            half8 a[4];
            #pragma unroll
            for (int j = 0; j < 4; ++j)
                a[j] = *reinterpret_cast<const half8*>(&h_full[l16][(kh * 4 + j) * 32 + quad * 8]);
            f32x4 gacc[4];
            #pragma unroll
            for (int g = 0; g < 4; ++g) { f32x4 z = {0.f,0.f,0.f,0.f}; gacc[g] = z; }
            #pragma unroll
            for (int j = 0; j < 4; ++j)
                #pragma unroll
                for (int g = 0; g < 4; ++g)
                    gacc[g] = mfma16(a[j], wl8[(((c * 4 + g) * 8) + kh * 4 + j) * 64 + lane], gacc[g]);
            if (w >= 4) {
                #pragma unroll
                for (int g = 0; g < 4; ++g)
                    *reinterpret_cast<f32x4*>(&pacc1[c][g][l16][quad * 4]) = gacc[g];
            }
            __syncthreads();   // (2)
            if (w < 4) {
                f32x4 p1[4];
                #pragma unroll
                for (int g = 0; g < 4; ++g)
                    p1[g] = *reinterpret_cast<const f32x4*>(&pacc1[c][g][l16][quad * 4]);
                const int hl = c * 16 + l16;
                union { unsigned long long u; unsigned short s[4]; } hp;
                #pragma unroll
                for (int r = 0; r < 4; ++r) {
                    float gi = gacc[0][r] + p1[0][r] + (tsvA[r] * wih[0] + bias[0]);
                    float gf = gacc[1][r] + p1[1][r] + (tsvA[r] * wih[1] + bias[1]);
                    float gg = gacc[2][r] + p1[2][r] + (tsvA[r] * wih[2] + bias[2]);
                    float go = gacc[3][r] + p1[3][r] + (tsvA[r] * wih[3] + bias[3]);
                    float I = __builtin_amdgcn_rcpf(1.0f + __builtin_amdgcn_exp2f(gi));
                    float F = __builtin_amdgcn_rcpf(1.0f + __builtin_amdgcn_exp2f(gf));
                    float G = 1.0f - 2.0f * __builtin_amdgcn_rcpf(1.0f + __builtin_amdgcn_exp2f(gg));
                    float O = __builtin_amdgcn_rcpf(1.0f + __builtin_amdgcn_exp2f(go));
                    float cn = F * cstA[r] + I * G;
                    cstA[r] = cn;
                    float tc = 1.0f - 2.0f * __builtin_amdgcn_rcpf(
                                   1.0f + __builtin_amdgcn_exp2f(2.0f * kLog2e * cn));
                    float hv = O * tc;
                    oaccA[r] += hv * wo;
                    _Float16 h16 = (_Float16)hv;
                    hp.s[r] = __builtin_bit_cast(unsigned short, h16);
                }
                ATS(gb64 + ((0 * 64 + bid) * 2 + wp) * 256 + (hl * 4 + quad), hp.u);
            }
        }

        // ================= phase B =================
        {
            if (t > 0) {
                while (ATL(&flags[64 + pbid]) < t) __builtin_amdgcn_s_sleep(1);
                asm volatile("" ::: "memory");
            }
            const unsigned long long* pt = gb64 + ((1 * 64 + pbid) * 2 + rp) * 256;
            unsigned long long d0 = ATL(pt + i0);
            unsigned long long d1 = ATL(pt + i0 + 1);
            union { unsigned long long u; unsigned short s[4]; } u0, u1;
            u0.u = d0; u1.u = d1;
            #pragma unroll
            for (int j = 0; j < 4; ++j) {
                reinterpret_cast<unsigned short*>(&h_full[cm0 + j][psub * 64 + chl])[0] = u0.s[j];
                reinterpret_cast<unsigned short*>(&h_full[cm0 + 4 + j][psub * 64 + chl])[0] = u1.s[j];
            }
        }
        __syncthreads();   // (3) h_full = set B; A publishes drained
        if (tid == 0) ATS(&flags[bid], t + 1);

        {
            half8 a[4];
            #pragma unroll
            for (int j = 0; j < 4; ++j)
                a[j] = *reinterpret_cast<const half8*>(&h_full[l16][(kh * 4 + j) * 32 + quad * 8]);
            f32x4 gacc[4];
            #pragma unroll
            for (int g = 0; g < 4; ++g) { f32x4 z = {0.f,0.f,0.f,0.f}; gacc[g] = z; }
            #pragma unroll
            for (int j = 0; j < 4; ++j)
                #pragma unroll
                for (int g = 0; g < 4; ++g)
                    gacc[g] = mfma16(a[j], wl8[(((c * 4 + g) * 8) + kh * 4 + j) * 64 + lane], gacc[g]);
            if (w >= 4) {
                #pragma unroll
                for (int g = 0; g < 4; ++g)
                    *reinterpret_cast<f32x4*>(&pacc1[c][g][l16][quad * 4]) = gacc[g];
            }
            __syncthreads();   // (4)
            if (w < 4) {
                f32x4 p1[4];
                #pragma unroll
                for (int g = 0; g < 4; ++g)
                    p1[g] = *reinterpret_cast<const f32x4*>(&pacc1[c][g][l16][quad * 4]);
                const int hl = c * 16 + l16;
                union { unsigned long long u; unsigned short s[4]; } hp;
                #pragma unroll
                for (int r = 0; r < 4; ++r) {
                    float gi = gacc[0][r] + p1[0][r] + (tsvB[r] * wih[0] + bias[0]);
                    float gf = gacc[1][r] + p1[1][r] + (tsvB[r] * wih[1] + bias[1]);
                    float gg = gacc[2][r] + p1[2][r] + (tsvB[r] * wih[2] + bias[2]);
                    float go = gacc[3][r] + p1[3][r] + (tsvB[r] * wih[3] + bias[3]);
                    float I = __builtin_amdgcn_rcpf(1.0f + __builtin_amdgcn_exp2f(gi));
                    float F = __builtin_amdgcn_rcpf(1.0f + __builtin_amdgcn_exp2f(gf));
                    float G = 1.0f - 2.0f * __builtin_amdgcn_rcpf(1.0f + __builtin_amdgcn_exp2f(gg));
                    float O = __builtin_amdgcn_rcpf(1.0f + __builtin_amdgcn_exp2f(go));
                    float cn = F * cstB[r] + I * G;
                    cstB[r] = cn;
                    float tc = 1.0f - 2.0f * __builtin_amdgcn_rcpf(
                                   1.0f + __builtin_amdgcn_exp2f(2.0f * kLog2e * cn));
                    float hv = O * tc;
                    oaccB[r] += hv * wo;
                    _Float16 h16 = (_Float16)hv;
                    hp.s[r] = __builtin_bit_cast(unsigned short, h16);
                }
                ATS(gb64 + ((1 * 64 + bid) * 2 + wp) * 256 + (hl * 4 + quad), hp.u);
            }
        }
        __syncthreads();   // (5) B publishes drained
        if (tid == 0) ATS(&flags[64 + bid], t + 1);
    }

    // ---- output partials ----
    if (w < 4) {
        #pragma unroll
        for (int r = 0; r < 4; ++r) {
            float vA = oaccA[r], vB = oaccB[r];
            vA += __shfl_xor(vA, 1, 64); vB += __shfl_xor(vB, 1, 64);
            vA += __shfl_xor(vA, 2, 64); vB += __shfl_xor(vB, 2, 64);
            vA += __shfl_xor(vA, 4, 64); vB += __shfl_xor(vB, 4, 64);
            vA += __shfl_xor(vA, 8, 64); vB += __shfl_xor(vB, 8, 64);
            oaccA[r] = vA; oaccB[r] = vB;
        }
        if (l16 == 0) {
            #pragma unroll
            for (int r = 0; r < 4; ++r) {
                red2[0][c][quad * 4 + r] = oaccA[r];
                red2[1][c][quad * 4 + r] = oaccB[r];
            }
        }
    }
    __syncthreads();
    if (tid < 32) {
        int set = tid >> 4, m = tid & 15;
        float s = 0.f;
        #pragma unroll
        for (int cc = 0; cc < 4; ++cc) s += red2[set][cc][m];
        pbuf[(set * 64 + bid) * 16 + m] = s;
    }
}

__global__ void finalize(const float* __restrict__ pbuf,
                         const float* __restrict__ b_out,
                         float* __restrict__ out)
{
    int b = blockIdx.x * blockDim.x + threadIdx.x;   // 0..511
    int grp = b >> 5, q = b & 31, set = q >> 4, m = q & 15;
    float s = b_out[0];
    #pragma unroll
    for (int s4 = 0; s4 < 4; ++s4)
        s += pbuf[(set * 64 + grp * 4 + s4) * 16 + m];
    out[b] = s;
}

extern "C" void kernel_launch(void* const* d_in, const int* in_sizes, int n_in,
                              void* d_out, int out_size, void* d_ws, size_t ws_size,
                              hipStream_t stream) {
    const float* ts    = (const float*)d_in[0];
    const float* W_ih  = (const float*)d_in[1];
    const float* W_hh  = (const float*)d_in[2];
    const float* b_ih  = (const float*)d_in[3];
    const float* b_hh  = (const float*)d_in[4];
    const float* W_out = (const float*)d_in[5];
    const float* b_out = (const float*)d_in[6];

    char* wsb = (char*)d_ws;
    _Float16*       wfrag = (_Float16*)wsb;
    unsigned short* gb    = (unsigned short*)(wsb + 524288);
    int*            flags = (int*)(wsb + 1048576);
    float*          pbuf  = (float*)(wsb + 1049088);

    hipMemsetAsync(wsb + 524288, 0, 524288 + 512 + 8192, stream);
    prep_weights<<<128, 256, 0, stream>>>(W_hh, wfrag);
    lstm_main<<<64, 512, 0, stream>>>(ts, W_ih, b_ih, b_hh, W_out,
                                      wfrag, gb, flags, pbuf);
    finalize<<<1, 512, 0, stream>>>(pbuf, b_out, (float*)d_out);
}